// Round 5
// baseline (1027.746 us; speedup 1.0000x reference)
//
#include <hip/hip_runtime.h>

#define N_ROWS 16384
#define N_EMB  8192
#define DIM    512
#define NCAND  16

#define GAS __attribute__((address_space(1)))
#define LAS __attribute__((address_space(3)))

// ---------------------------------------------------------------------------
// ws layout:
//   [0]    double lossAcc (16 B, zeroed)
//   [16]   int cand[N_ROWS * NCAND]   (1 MB)
// k_hot region (512 MB at d_out + 33554436 B) is scratch BEFORE rescore:
//   +12 B          : blkTop u32[N_ROWS*64*8]   (32 MB) per-block top-8 keys
//   +12+32 MB      : ze_bf16 u16[N_ROWS*DIM]   (16.8 MB)
//   then           : cb_bf16 u16[N_EMB*DIM]    ( 8.4 MB)
// Consumed by gemm/merge (stream-ordered before rescore overwrites k_hot).
// ---------------------------------------------------------------------------

typedef short  bhalf8  __attribute__((ext_vector_type(8)));
typedef float  floatx4 __attribute__((ext_vector_type(4)));

__device__ __forceinline__ unsigned short f2b(float f) {
    unsigned u = __builtin_bit_cast(unsigned, f);
    unsigned r = (u + 0x7fffu + ((u >> 16) & 1u)) >> 16;   // RNE
    return (unsigned short)r;
}
__device__ __forceinline__ unsigned pk2(float a, float b) {
    return (unsigned)f2b(a) | ((unsigned)f2b(b) << 16);
}
// sortable key: ascending u32 == ascending (score, col); lower col wins ties
__device__ __forceinline__ unsigned mkkey(float s, int col) {
    unsigned short b = f2b(s);
    unsigned short ts = (unsigned short)(b ^ ((b & 0x8000u) ? 0xFFFFu : 0x8000u));
    return ((unsigned)ts << 16) | (unsigned)col;
}
__device__ __forceinline__ unsigned umn(unsigned a, unsigned b) { return a < b ? a : b; }

// fp32 -> bf16 one-time conversion of both inputs (8 elements/thread).
__global__ void convert_bf16_kernel(const float* __restrict__ ze,
                                    const float* __restrict__ cb,
                                    unsigned short* __restrict__ ze16,
                                    unsigned short* __restrict__ cb16) {
    size_t id = (size_t)blockIdx.x * 256 + threadIdx.x;
    const size_t nze = (size_t)N_ROWS * DIM / 8;
    const float* src;
    unsigned short* dst;
    size_t off;
    if (id < nze) { src = ze; dst = ze16; off = id * 8; }
    else          { src = cb; dst = cb16; off = (id - nze) * 8; }
    float4 a = *(const float4*)(src + off);
    float4 b = *(const float4*)(src + off + 4);
    uint4 u = { pk2(a.x, a.y), pk2(a.z, a.w), pk2(b.x, b.y), pk2(b.z, b.w) };
    *(uint4*)(dst + off) = u;
}

// Phase 1a: bf16 MFMA GEMM fused with per-block per-row top-8.
// R13: 256x256 tile, BK=64, 512 threads, 8 waves as 4M x 2N (wave output
// 64 rows x 128 cols), 8-phase counted-vmcnt schedule (T3+T4+T5 per the
// catalog; the 2-phase 128^2 structure was ceiling'd at ~513 TF across
// R10-R12 with MfmaUtil ~17%).
//   - per K-tile: 4 phases {(k0,m0),(k0,m1),(k1,m0),(k1,m1)}, 16 MFMA each
//     between raw s_barriers; B-frags (8x b128) cached across m-half phases
//     -> 24 ds_read_b128/wave/K-tile (LDS ~41us/CU < MFMA ~64us/CU).
//   - staging: tile t+1's A issued in t.P0, B in t.P1, into the buffer
//     freed at t-1's end (race-free); single vmcnt(0) per K-tile placed
//     BEFORE the tile-end barrier (certification: each wave drains its own
//     loads, barrier publishes) -- loads stay in flight across the 7
//     interior barriers, 2-4 phases of landing slack.
//   - wave owns 128 cols => per-row top-8 geometry identical to R12;
//     col-block = cblk*2 + wc => blkTop bytes identical; merge unchanged.
//   - proven pieces kept: XOR chunk swizzle (0 bank conflicts in R9 PMC),
//     global_load_lds width 16 with linear LDS dest, XCD-bijective grid,
//     lgkmcnt(0)+sched_barrier(0) before MFMA (rule 18), setprio (T5).
__launch_bounds__(512, 2)
__global__ void score_gemm_topk_kernel(const unsigned short* __restrict__ ze16,
                                       const unsigned short* __restrict__ cb16,
                                       unsigned* __restrict__ blkTop) {
    __shared__ unsigned short Amm[2][256 * 64];   // 2 x 32 KB
    __shared__ unsigned short Bmm[2][256 * 64];   // 2 x 32 KB (total 128 KB)

    const int th   = threadIdx.x;
    const int lane = th & 63;
    const int w    = th >> 6;        // 0..7
    const int wr   = w >> 1;         // 0..3 (M quarter)
    const int wc   = w & 1;          // 0..1 (N half)

    // XCD-aware bijective decode: 2048 blocks, xcd = bid&7 owns 4 col-tiles
    // (4 x 256 cols x 512 K x 2B = 1 MB cb16 slice, L2-resident).
    const int bid   = blockIdx.x;              // 0..2047
    const int xcd   = bid & 7;
    const int chunk = bid >> 3;                // 0..255
    const int cblk  = xcd * 4 + (chunk & 3);   // col-tile (256-wide) 0..31
    const int rblk  = chunk >> 2;              // row-tile 0..63
    const int rowBase = rblk * 256;
    const int colBase = cblk * 256;

    const int m = lane & 15;
    const int q = lane >> 4;

    floatx4 acc[4][8];
    #pragma unroll
    for (int i = 0; i < 4; ++i)
        #pragma unroll
        for (int j = 0; j < 8; ++j)
            acc[i][j] = (floatx4){0.0f, 0.0f, 0.0f, 0.0f};

    // staging: call k covers tile rows k*64 + (th>>3); phys chunk th&7 holds
    // global chunk (th&7) ^ (row&7). Dest = linear in thread id (16 B/lane).
    const int tr = th >> 3;          // 0..63
    const int tc = th & 7;
    const int cg = tc ^ (tr & 7);
    const unsigned short* pa = ze16 + (size_t)(rowBase + tr) * DIM + cg * 8;
    const unsigned short* pb = cb16 + (size_t)(colBase + tr) * DIM + cg * 8;

    // frag chunk offsets (elements): logical chunk ksub*4+q, row-swizzle m&7
    const int ch0 = ((0 * 4 + q) ^ (m & 7)) * 8;
    const int ch1 = ((1 * 4 + q) ^ (m & 7)) * 8;

#define STG_A(bb, koff)                                                        \
    do {                                                                       \
        _Pragma("unroll")                                                      \
        for (int k2 = 0; k2 < 4; ++k2)                                         \
            __builtin_amdgcn_global_load_lds(                                  \
                (const GAS void*)(pa + (size_t)k2 * 64 * DIM + (koff)),        \
                (LAS void*)(&Amm[bb][(k2 * 64 + tr) * 64 + tc * 8]), 16, 0, 0);\
    } while (0)
#define STG_B(bb, koff)                                                        \
    do {                                                                       \
        _Pragma("unroll")                                                      \
        for (int k2 = 0; k2 < 4; ++k2)                                         \
            __builtin_amdgcn_global_load_lds(                                  \
                (const GAS void*)(pb + (size_t)k2 * 64 * DIM + (koff)),        \
                (LAS void*)(&Bmm[bb][(k2 * 64 + tr) * 64 + tc * 8]), 16, 0, 0);\
    } while (0)

// One phase: ds_reads -> stage issues -> barrier -> lgkm drain -> 16 MFMA
// -> [tile-end: own-vmcnt drain] -> barrier.
#define PHASE(BB, CH, MH, STAGE_STMT, ENDTILE)                                 \
    {                                                                          \
        bhalf8 a0 = *(bhalf8*)&Amm[BB][(wr * 64 + ((MH) * 2 + 0) * 16 + m) * 64 + (CH)]; \
        bhalf8 a1 = *(bhalf8*)&Amm[BB][(wr * 64 + ((MH) * 2 + 1) * 16 + m) * 64 + (CH)]; \
        if ((MH) == 0) {                                                       \
            _Pragma("unroll")                                                  \
            for (int n = 0; n < 8; ++n)                                        \
                bfr[n] = *(bhalf8*)&Bmm[BB][(wc * 128 + n * 16 + m) * 64 + (CH)]; \
        }                                                                      \
        STAGE_STMT;                                                            \
        __builtin_amdgcn_s_barrier();                                          \
        asm volatile("s_waitcnt lgkmcnt(0)" ::: "memory");                     \
        __builtin_amdgcn_sched_barrier(0);                                     \
        __builtin_amdgcn_s_setprio(1);                                         \
        _Pragma("unroll")                                                      \
        for (int n = 0; n < 8; ++n) {                                          \
            acc[(MH) * 2 + 0][n] = __builtin_amdgcn_mfma_f32_16x16x32_bf16(a0, bfr[n], acc[(MH) * 2 + 0][n], 0, 0, 0); \
            acc[(MH) * 2 + 1][n] = __builtin_amdgcn_mfma_f32_16x16x32_bf16(a1, bfr[n], acc[(MH) * 2 + 1][n], 0, 0, 0); \
        }                                                                      \
        __builtin_amdgcn_s_setprio(0);                                         \
        if (ENDTILE) { asm volatile("s_waitcnt vmcnt(0)" ::: "memory"); }      \
        __builtin_amdgcn_s_barrier();                                          \
    }

    bhalf8 bfr[8];

    // prologue: stage K-tile 0 into buf0; certify; go.
    STG_A(0, 0);
    STG_B(0, 0);
    asm volatile("s_waitcnt vmcnt(0)" ::: "memory");
    __builtin_amdgcn_s_barrier();

    #pragma unroll 1
    for (int i = 0; i < 4; ++i) {
        const unsigned ko1 = (unsigned)(2 * i + 1) * 64;   // K-offset, tile 2i+1
        const unsigned ko2 = ko1 + 64;                     // K-offset, tile 2i+2
        // ---- tile t = 2i (buf0); stage t+1 -> buf1 ----
        PHASE(0, ch0, 0, STG_A(1, ko1), 0)
        PHASE(0, ch0, 1, STG_B(1, ko1), 0)
        PHASE(0, ch1, 0, ;, 0)
        PHASE(0, ch1, 1, ;, 1)
        // ---- tile t = 2i+1 (buf1); stage t+2 -> buf0 (except last) ----
        PHASE(1, ch0, 0, if (i < 3) STG_A(0, ko2), 0)
        PHASE(1, ch0, 1, if (i < 3) STG_B(0, ko2), 0)
        PHASE(1, ch1, 0, ;, 0)
        PHASE(1, ch1, 1, ;, 1)
    }
#undef PHASE
#undef STG_A
#undef STG_B

    // Epilogue: per (mrep,reg), 16-lane group holds 128 keys (8/lane);
    // Batcher sort-8 + 4 bitonic cross-lane merge levels (R12-proven,
    // bit-identical to extract-min). Wave covers 64 rows x 128 cols;
    // col-block index = cblk*2 + wc (same 64 x 128-col blocks as before).
    const int cblk2 = cblk * 2 + wc;
#define CE(x, y) { unsigned _lo = umn(kk[x], kk[y]);                         \
                   unsigned _hi = kk[x] < kk[y] ? kk[y] : kk[x];             \
                   kk[x] = _lo; kk[y] = _hi; }
    #pragma unroll
    for (int mrep = 0; mrep < 4; ++mrep) {
        #pragma unroll
        for (int reg = 0; reg < 4; ++reg) {
            const int grow = rowBase + wr * 64 + mrep * 16 + q * 4 + reg;
            unsigned kk[8];
            #pragma unroll
            for (int j = 0; j < 8; ++j)
                kk[j] = mkkey(-acc[mrep][j][reg], colBase + wc * 128 + j * 16 + m);

            // Batcher odd-even mergesort, 8 elements, 19 CE -> ascending
            CE(0,1) CE(2,3) CE(4,5) CE(6,7)
            CE(0,2) CE(1,3) CE(4,6) CE(5,7)
            CE(1,2) CE(5,6)
            CE(0,4) CE(1,5) CE(2,6) CE(3,7)
            CE(2,4) CE(3,5)
            CE(1,2) CE(3,4) CE(5,6)

            // 4 bitonic merge levels across lanes (xor 1,2,4,8 within the
            // 16-lane group): keep bottom-8 multiset, 12-CE clean each.
            #pragma unroll
            for (int d = 1; d <= 8; d <<= 1) {
                unsigned p[8];
                #pragma unroll
                for (int u = 0; u < 8; ++u)
                    p[u] = (unsigned)__shfl_xor((int)kk[u], d, 64);
                #pragma unroll
                for (int u = 0; u < 8; ++u)
                    kk[u] = umn(kk[u], p[7 - u]);
                CE(0,4) CE(1,5) CE(2,6) CE(3,7)
                CE(0,2) CE(1,3) CE(4,6) CE(5,7)
                CE(0,1) CE(2,3) CE(4,5) CE(6,7)
            }

            if (m == 0) {
                uint4* dst = (uint4*)&blkTop[((size_t)grow * 64 + cblk2) * 8];
                uint4 lo4 = { kk[0], kk[1], kk[2], kk[3] };
                uint4 hi4 = { kk[4], kk[5], kk[6], kk[7] };
                dst[0] = lo4;
                dst[1] = hi4;
            }
        }
    }
#undef CE
}

// Phase 1b: merge 64 blocks x 8 keys per row -> top-16 candidates.
__global__ void merge_topk_kernel(const unsigned* __restrict__ blkTop,
                                  int* __restrict__ cand) {
    const int wv   = threadIdx.x >> 6;
    const int lane = threadIdx.x & 63;
    const int row  = blockIdx.x * 4 + wv;
    const uint4* base = (const uint4*)(blkTop + (size_t)row * 512);

    uint4 a = base[lane * 2];
    uint4 b = base[lane * 2 + 1];
    unsigned in[8] = { a.x, a.y, a.z, a.w, b.x, b.y, b.z, b.w };
    unsigned kk[8];
    #pragma unroll
    for (int j = 0; j < 8; ++j) {
        kk[j] = in[j];
        #pragma unroll
        for (int s = 7; s > 0; --s) {
            if (s <= j) {
                unsigned lo = umn(kk[s - 1], kk[s]);
                unsigned hi = kk[s - 1] < kk[s] ? kk[s] : kk[s - 1];
                kk[s - 1] = lo; kk[s] = hi;
            }
        }
    }

    unsigned sval = 0;
    #pragma unroll
    for (int s = 0; s < NCAND; ++s) {
        unsigned g = kk[0];
        #pragma unroll
        for (int d = 32; d; d >>= 1)
            g = umn(g, (unsigned)__shfl_xor((int)g, d, 64));
        bool pop = (kk[0] == g);
        #pragma unroll
        for (int u = 0; u < 7; ++u) kk[u] = pop ? kk[u + 1] : kk[u];
        kk[7] = pop ? 0xFFFFFFFFu : kk[7];
        sval = (lane == s) ? g : sval;
    }
    if (lane < NCAND)
        cand[(size_t)row * NCAND + lane] = (int)(sval & 0xFFFFu);
}

// Phase 2: exact numpy-fp32 replica rescore (selection logic unchanged since
// R4) + FULL k_hot row write (zeros + the 4 ones in one pass; replaces the
// 512 MB memset).
__global__ void rescore_kernel(const float* __restrict__ ze,
                               const float* __restrict__ cb,
                               const int* __restrict__ cand,
                               float* __restrict__ out_zq,
                               float* __restrict__ out_khot,
                               double* __restrict__ lossAcc) {
    __shared__ float zsh[4][DIM];
    const int wv = threadIdx.x >> 6;
    const int lane = threadIdx.x & 63;
    const int row = blockIdx.x * 4 + wv;

    {
        const float* zp = ze + (size_t)row * DIM + lane * 8;
        float4 v0 = *(const float4*)zp;
        float4 v1 = *(const float4*)(zp + 4);
        *(float4*)&zsh[wv][lane * 8]     = v0;
        *(float4*)&zsh[wv][lane * 8 + 4] = v1;
    }
    __syncthreads();

    // znorm, numpy-pairwise
    float racc = 0.0f;
    {
        const int b = (lane >> 3) & 3;
        const int j = lane & 7;
        const float* zr = &zsh[wv][128 * b + j];
        #pragma unroll
        for (int i = 0; i < 16; ++i) {
            float zk = zr[8 * i];
            float sq = zk * zk;
            asm volatile("" : "+v"(sq));   // block FMA contraction into the add
            racc = racc + sq;
        }
    }
    float t1 = racc + __shfl_xor(racc, 1, 64);
    float t2 = t1 + __shfl_xor(t1, 2, 64);
    float t3 = t2 + __shfl_xor(t2, 4, 64);
    float zn = (__shfl(t3, 0, 64) + __shfl(t3, 8, 64))
             + (__shfl(t3, 16, 64) + __shfl(t3, 24, 64));

    // candidate chains: KC=384 split, sequential FMA, single accumulator each
    float qv = 3.0e38f;
    int   idxv = 0x7fffffff;
    if (lane < NCAND) {
        idxv = cand[(size_t)row * NCAND + lane];
        const float* wp = cb + (size_t)idxv * DIM;
        const float* zz = zsh[wv];
        float acc1 = 0.0f;
        for (int k = 0; k < 384; k += 8) {
            float4 wa = *(const float4*)(wp + k);
            float4 wb = *(const float4*)(wp + k + 4);
            acc1 = __builtin_fmaf(zz[k + 0], wa.x, acc1);
            acc1 = __builtin_fmaf(zz[k + 1], wa.y, acc1);
            acc1 = __builtin_fmaf(zz[k + 2], wa.z, acc1);
            acc1 = __builtin_fmaf(zz[k + 3], wa.w, acc1);
            acc1 = __builtin_fmaf(zz[k + 4], wb.x, acc1);
            acc1 = __builtin_fmaf(zz[k + 5], wb.y, acc1);
            acc1 = __builtin_fmaf(zz[k + 6], wb.z, acc1);
            acc1 = __builtin_fmaf(zz[k + 7], wb.w, acc1);
        }
        float acc2 = 0.0f;
        for (int k = 384; k < 512; k += 8) {
            float4 wa = *(const float4*)(wp + k);
            float4 wb = *(const float4*)(wp + k + 4);
            acc2 = __builtin_fmaf(zz[k + 0], wa.x, acc2);
            acc2 = __builtin_fmaf(zz[k + 1], wa.y, acc2);
            acc2 = __builtin_fmaf(zz[k + 2], wa.z, acc2);
            acc2 = __builtin_fmaf(zz[k + 3], wa.w, acc2);
            acc2 = __builtin_fmaf(zz[k + 4], wb.x, acc2);
            acc2 = __builtin_fmaf(zz[k + 5], wb.y, acc2);
            acc2 = __builtin_fmaf(zz[k + 6], wb.z, acc2);
            acc2 = __builtin_fmaf(zz[k + 7], wb.w, acc2);
        }
        float Cv = acc1 + acc2;
        qv = zn - 2.0f * Cv;
    }

    float q[NCAND]; int id[NCAND];
    #pragma unroll
    for (int c = 0; c < NCAND; ++c) {
        q[c]  = __shfl(qv, c, 64);
        id[c] = __shfl(idxv, c, 64);
    }
    int selIdx[4];
    bool used[NCAND];
    #pragma unroll
    for (int c = 0; c < NCAND; ++c) used[c] = false;
    #pragma unroll
    for (int s = 0; s < 4; ++s) {
        float bq = 3.0e38f; int bi = 0x7fffffff; int bc = -1;
        #pragma unroll
        for (int c = 0; c < NCAND; ++c) {
            bool better = !used[c] && (q[c] < bq || (q[c] == bq && id[c] < bi));
            if (better) { bq = q[c]; bi = id[c]; bc = c; }
        }
        selIdx[s] = bi;
        #pragma unroll
        for (int c = 0; c < NCAND; ++c) used[c] = used[c] || (c == bc);
    }

    float zq[8] = { 0, 0, 0, 0, 0, 0, 0, 0 };
    #pragma unroll
    for (int s = 0; s < 4; ++s) {
        const float* wp = cb + (size_t)selIdx[s] * DIM + lane * 8;
        float4 w0 = *(const float4*)wp;
        float4 w1 = *(const float4*)(wp + 4);
        zq[0] += w0.x; zq[1] += w0.y; zq[2] += w0.z; zq[3] += w0.w;
        zq[4] += w1.x; zq[5] += w1.y; zq[6] += w1.z; zq[7] += w1.w;
    }

    float zf[8];
    {
        const float* zz = &zsh[wv][lane * 8];
        #pragma unroll
        for (int i = 0; i < 8; ++i) zf[i] = zz[i];
    }
    float o[8];
    double l = 0.0;
    #pragma unroll
    for (int i = 0; i < 8; ++i) {
        float zqf  = zq[i] * 0.25f;
        float diff = zqf - zf[i];
        o[i] = zf[i] + diff;
        double ld = (double)diff;
        l += ld * ld;
    }
    {
        float* op = out_zq + (size_t)row * DIM + lane * 8;
        float4 v0 = { o[0], o[1], o[2], o[3] };
        float4 v1 = { o[4], o[5], o[6], o[7] };
        *(float4*)op = v0;
        *(float4*)(op + 4) = v1;
    }
    #pragma unroll
    for (int mm = 32; mm; mm >>= 1) l += __shfl_xor(l, mm, 64);
    if (lane == 0) atomicAdd(lossAcc, l);

    // full k_hot row write: lane owns cols {j*256 + lane*4 + e}.
    // hot mask: col -> j = col>>8, e = col&3, owner lane = (col>>2)&63.
    unsigned hotm[4] = { 0u, 0u, 0u, 0u };
    #pragma unroll
    for (int s = 0; s < 4; ++s) {
        int si = selIdx[s];
        bool own = ((si >> 2) & 63) == lane;
        int jj = si >> 8;
        unsigned bit = 1u << (((jj & 7) << 2) | (si & 3));
        int word = jj >> 3;
        #pragma unroll
        for (int wd = 0; wd < 4; ++wd)
            hotm[wd] |= (own && word == wd) ? bit : 0u;
    }
    float* kp = out_khot + (size_t)row * N_EMB;
    #pragma unroll
    for (int j = 0; j < 32; ++j) {
        unsigned bits = (hotm[j >> 3] >> ((j & 7) * 4)) & 0xFu;
        float4 v;
        v.x = (bits & 1u) ? 1.0f : 0.0f;
        v.y = (bits & 2u) ? 1.0f : 0.0f;
        v.z = (bits & 4u) ? 1.0f : 0.0f;
        v.w = (bits & 8u) ? 1.0f : 0.0f;
        *(float4*)(kp + j * 256 + lane * 4) = v;
    }
}

__global__ void finalize_kernel(const double* __restrict__ lossAcc,
                                float* __restrict__ out_loss) {
    if (threadIdx.x == 0 && blockIdx.x == 0)
        out_loss[0] = (float)(lossAcc[0] * (1.25 / ((double)N_ROWS * (double)DIM)));
}

extern "C" void kernel_launch(void* const* d_in, const int* in_sizes, int n_in,
                              void* d_out, int out_size, void* d_ws, size_t ws_size,
                              hipStream_t stream) {
    (void)in_sizes; (void)n_in; (void)out_size; (void)ws_size;
    const float* ze = (const float*)d_in[0];
    const float* cb = (const float*)d_in[1];

    float* out      = (float*)d_out;
    float* out_zq   = out;                                   // [16384, 512]
    float* out_loss = out + (size_t)N_ROWS * DIM;            // [1]
    float* out_khot = out_loss + 1;                          // [16384, 8192]

    double* lossAcc = (double*)d_ws;
    int*    cand    = (int*)((char*)d_ws + 16);

    // scratch inside k_hot region, 16B-aligned, consumed before rescore
    char* base = (char*)d_out;
    unsigned*       blkTop = (unsigned*)(base + 33554448);                  // khot + 12 B
    unsigned short* ze16   = (unsigned short*)(base + 33554448 + 33554432); // + 32 MB
    unsigned short* cb16   = ze16 + (size_t)N_ROWS * DIM;

    hipMemsetAsync(lossAcc, 0, 16, stream);

    convert_bf16_kernel<<<6144, 256, 0, stream>>>(ze, cb, ze16, cb16);
    score_gemm_topk_kernel<<<2048, 512, 0, stream>>>(ze16, cb16, blkTop);
    merge_topk_kernel<<<N_ROWS / 4, 256, 0, stream>>>(blkTop, cand);
    rescore_kernel<<<N_ROWS / 4, 256, 0, stream>>>(ze, cb, cand, out_zq, out_khot, lossAcc);
    finalize_kernel<<<1, 64, 0, stream>>>(lossAcc, out_loss);
}

// Round 6
// 1025.049 us; speedup vs baseline: 1.0026x; 1.0026x over previous
//
#include <hip/hip_runtime.h>

#define N_ROWS 16384
#define N_EMB  8192
#define DIM    512
#define NCAND  16

#define GAS __attribute__((address_space(1)))
#define LAS __attribute__((address_space(3)))

// ---------------------------------------------------------------------------
// ws layout:
//   [0]    double lossAcc (16 B, zeroed)
//   [16]   int cand[N_ROWS * NCAND]   (1 MB)
// k_hot region (512 MB at d_out + 33554436 B) is scratch BEFORE rescore:
//   +12 B          : blkTop u32[N_ROWS*64*8]   (32 MB) per-block top-8 keys
//   +12+32 MB      : ze_bf16 u16[N_ROWS*DIM]   (16.8 MB)
//   then           : cb_bf16 u16[N_EMB*DIM]    ( 8.4 MB)
// Consumed by gemm/merge (stream-ordered before rescore overwrites k_hot).
// ---------------------------------------------------------------------------

typedef short  bhalf8  __attribute__((ext_vector_type(8)));
typedef float  floatx4 __attribute__((ext_vector_type(4)));

__device__ __forceinline__ unsigned short f2b(float f) {
    unsigned u = __builtin_bit_cast(unsigned, f);
    unsigned r = (u + 0x7fffu + ((u >> 16) & 1u)) >> 16;   // RNE
    return (unsigned short)r;
}
__device__ __forceinline__ unsigned pk2(float a, float b) {
    return (unsigned)f2b(a) | ((unsigned)f2b(b) << 16);
}
// sortable key: ascending u32 == ascending (score, col); lower col wins ties
__device__ __forceinline__ unsigned mkkey(float s, int col) {
    unsigned short b = f2b(s);
    unsigned short ts = (unsigned short)(b ^ ((b & 0x8000u) ? 0xFFFFu : 0x8000u));
    return ((unsigned)ts << 16) | (unsigned)col;
}
__device__ __forceinline__ unsigned umn(unsigned a, unsigned b) { return a < b ? a : b; }

// fp32 -> bf16 one-time conversion of both inputs (8 elements/thread).
__global__ void convert_bf16_kernel(const float* __restrict__ ze,
                                    const float* __restrict__ cb,
                                    unsigned short* __restrict__ ze16,
                                    unsigned short* __restrict__ cb16) {
    size_t id = (size_t)blockIdx.x * 256 + threadIdx.x;
    const size_t nze = (size_t)N_ROWS * DIM / 8;
    const float* src;
    unsigned short* dst;
    size_t off;
    if (id < nze) { src = ze; dst = ze16; off = id * 8; }
    else          { src = cb; dst = cb16; off = (id - nze) * 8; }
    float4 a = *(const float4*)(src + off);
    float4 b = *(const float4*)(src + off + 4);
    uint4 u = { pk2(a.x, a.y), pk2(a.z, a.w), pk2(b.x, b.y), pk2(b.z, b.w) };
    *(uint4*)(dst + off) = u;
}

// Phase 1a: bf16 MFMA GEMM fused with per-block per-row top-8.
// R14 = R13 geometry (256x256, BK=64, 512 thr, 8 waves as 4M x 2N, wave
// output 64 rows x 128 cols -> blkTop bytes identical) with the phase split
// changed from (ksub, M-half) to (ksub, N-half).
// R13 post-mortem (m196 failure mode): MH0 phases front-loaded 10x
// ds_read_b128 (2A + all 8 B-frags) behind one lgkmcnt(0) -> ~960 cyc of
// serialized LDS vs ~620 cyc MFMA per CU per phase; the drain was the
// critical path. New split: phase = 4m x 4n x 1ksub = 16 MFMA; reads
// p(k,nh0) = 4A + 4B = 8, p(k,nh1) = 4B (A held in regs) = 4. Max spike
// 10 -> 8, B-frags read JIT in their consuming phase.
// Kept from R13 (all proven, absmax 0.0): staging order (ds_read -> G-load
// issue -> barrier -> lgkm drain -> MFMA), per-tile own-load vmcnt(0) at
// phases 4/8 only (loads fly across 7 interior raw barriers), setprio
// around MFMA (T5), sched_barrier(0) after inline lgkm (rule 18), XOR
// chunk swizzle (0 bank conflicts, R9 PMC), global_load_lds width 16
// linear dest, XCD-bijective grid.
__launch_bounds__(512, 2)
__global__ void score_gemm_topk_kernel(const unsigned short* __restrict__ ze16,
                                       const unsigned short* __restrict__ cb16,
                                       unsigned* __restrict__ blkTop) {
    __shared__ unsigned short Amm[2][256 * 64];   // 2 x 32 KB
    __shared__ unsigned short Bmm[2][256 * 64];   // 2 x 32 KB (total 128 KB)

    const int th   = threadIdx.x;
    const int lane = th & 63;
    const int w    = th >> 6;        // 0..7
    const int wr   = w >> 1;         // 0..3 (M quarter)
    const int wc   = w & 1;          // 0..1 (N half)

    // XCD-aware bijective decode: 2048 blocks, xcd = bid&7 owns 4 col-tiles
    // (1 MB cb16 slice, L2-resident).
    const int bid   = blockIdx.x;              // 0..2047
    const int xcd   = bid & 7;
    const int chunk = bid >> 3;                // 0..255
    const int cblk  = xcd * 4 + (chunk & 3);   // col-tile (256-wide) 0..31
    const int rblk  = chunk >> 2;              // row-tile 0..63
    const int rowBase = rblk * 256;
    const int colBase = cblk * 256;

    const int m = lane & 15;
    const int q = lane >> 4;

    floatx4 acc[4][8];
    #pragma unroll
    for (int i = 0; i < 4; ++i)
        #pragma unroll
        for (int j = 0; j < 8; ++j)
            acc[i][j] = (floatx4){0.0f, 0.0f, 0.0f, 0.0f};

    // staging: call k covers tile rows k*64 + (th>>3); phys chunk th&7 holds
    // global chunk (th&7) ^ (row&7). Dest = linear in thread id (16 B/lane).
    const int tr = th >> 3;          // 0..63
    const int tc = th & 7;
    const int cg = tc ^ (tr & 7);
    const unsigned short* pa = ze16 + (size_t)(rowBase + tr) * DIM + cg * 8;
    const unsigned short* pb = cb16 + (size_t)(colBase + tr) * DIM + cg * 8;

#define STG_A(bb, koff)                                                        \
    do {                                                                       \
        _Pragma("unroll")                                                      \
        for (int k2 = 0; k2 < 4; ++k2)                                         \
            __builtin_amdgcn_global_load_lds(                                  \
                (const GAS void*)(pa + (size_t)k2 * 64 * DIM + (koff)),        \
                (LAS void*)(&Amm[bb][(k2 * 64 + tr) * 64 + tc * 8]), 16, 0, 0);\
    } while (0)
#define STG_B(bb, koff)                                                        \
    do {                                                                       \
        _Pragma("unroll")                                                      \
        for (int k2 = 0; k2 < 4; ++k2)                                         \
            __builtin_amdgcn_global_load_lds(                                  \
                (const GAS void*)(pb + (size_t)k2 * 64 * DIM + (koff)),        \
                (LAS void*)(&Bmm[bb][(k2 * 64 + tr) * 64 + tc * 8]), 16, 0, 0);\
    } while (0)

// One phase (KS = ksub 0/1, NH = N-half 0/1): ds_reads (4A if NH==0, +4B)
// -> stage issue -> barrier -> lgkm drain -> 16 MFMA -> [tile-end vmcnt] ->
// barrier. A-frags for KS are loaded in the NH0 phase and reused in NH1.
#define PHASE(BB, KS, NH, STAGE_STMT, ENDTILE)                                 \
    {                                                                          \
        const int chx = (((KS) * 4 + q) ^ (m & 7)) * 8;                        \
        if ((NH) == 0) {                                                       \
            _Pragma("unroll")                                                  \
            for (int mf = 0; mf < 4; ++mf)                                     \
                aA[mf] = *(bhalf8*)&Amm[BB][(wr * 64 + mf * 16 + m) * 64 + chx]; \
        }                                                                      \
        _Pragma("unroll")                                                      \
        for (int nf = 0; nf < 4; ++nf)                                         \
            bfr[nf] = *(bhalf8*)&Bmm[BB][(wc * 128 + ((NH) * 4 + nf) * 16 + m) * 64 + chx]; \
        STAGE_STMT;                                                            \
        __builtin_amdgcn_s_barrier();                                          \
        asm volatile("s_waitcnt lgkmcnt(0)" ::: "memory");                     \
        __builtin_amdgcn_sched_barrier(0);                                     \
        __builtin_amdgcn_s_setprio(1);                                         \
        _Pragma("unroll")                                                      \
        for (int mf = 0; mf < 4; ++mf) {                                       \
            _Pragma("unroll")                                                  \
            for (int nf = 0; nf < 4; ++nf)                                     \
                acc[mf][(NH) * 4 + nf] = __builtin_amdgcn_mfma_f32_16x16x32_bf16( \
                    aA[mf], bfr[nf], acc[mf][(NH) * 4 + nf], 0, 0, 0);         \
        }                                                                      \
        __builtin_amdgcn_s_setprio(0);                                         \
        if (ENDTILE) { asm volatile("s_waitcnt vmcnt(0)" ::: "memory"); }      \
        __builtin_amdgcn_s_barrier();                                          \
    }

    bhalf8 aA[4];
    bhalf8 bfr[4];

    // prologue: stage K-tile 0 into buf0; certify; go.
    STG_A(0, 0);
    STG_B(0, 0);
    asm volatile("s_waitcnt vmcnt(0)" ::: "memory");
    __builtin_amdgcn_s_barrier();

    #pragma unroll 1
    for (int i = 0; i < 4; ++i) {
        const unsigned ko1 = (unsigned)(2 * i + 1) * 64;   // K-offset, tile 2i+1
        const unsigned ko2 = ko1 + 64;                     // K-offset, tile 2i+2
        // ---- tile t = 2i (buf0); stage t+1 -> buf1 in p0/p1 ----
        PHASE(0, 0, 0, STG_A(1, ko1), 0)
        PHASE(0, 0, 1, STG_B(1, ko1), 0)
        PHASE(0, 1, 0, ;, 0)
        PHASE(0, 1, 1, ;, 1)
        // ---- tile t = 2i+1 (buf1); stage t+2 -> buf0 (except last) ----
        PHASE(1, 0, 0, if (i < 3) STG_A(0, ko2), 0)
        PHASE(1, 0, 1, if (i < 3) STG_B(0, ko2), 0)
        PHASE(1, 1, 0, ;, 0)
        PHASE(1, 1, 1, ;, 1)
    }
#undef PHASE
#undef STG_A
#undef STG_B

    // Epilogue: per (mrep,reg), 16-lane group holds 128 keys (8/lane);
    // Batcher sort-8 + 4 bitonic cross-lane merge levels (R12-proven,
    // bit-identical to extract-min). Wave covers 64 rows x 128 cols;
    // col-block index = cblk*2 + wc (same 64 x 128-col blocks as before).
    const int cblk2 = cblk * 2 + wc;
#define CE(x, y) { unsigned _lo = umn(kk[x], kk[y]);                         \
                   unsigned _hi = kk[x] < kk[y] ? kk[y] : kk[x];             \
                   kk[x] = _lo; kk[y] = _hi; }
    #pragma unroll
    for (int mrep = 0; mrep < 4; ++mrep) {
        #pragma unroll
        for (int reg = 0; reg < 4; ++reg) {
            const int grow = rowBase + wr * 64 + mrep * 16 + q * 4 + reg;
            unsigned kk[8];
            #pragma unroll
            for (int j = 0; j < 8; ++j)
                kk[j] = mkkey(-acc[mrep][j][reg], colBase + wc * 128 + j * 16 + m);

            // Batcher odd-even mergesort, 8 elements, 19 CE -> ascending
            CE(0,1) CE(2,3) CE(4,5) CE(6,7)
            CE(0,2) CE(1,3) CE(4,6) CE(5,7)
            CE(1,2) CE(5,6)
            CE(0,4) CE(1,5) CE(2,6) CE(3,7)
            CE(2,4) CE(3,5)
            CE(1,2) CE(3,4) CE(5,6)

            // 4 bitonic merge levels across lanes (xor 1,2,4,8 within the
            // 16-lane group): keep bottom-8 multiset, 12-CE clean each.
            #pragma unroll
            for (int d = 1; d <= 8; d <<= 1) {
                unsigned p[8];
                #pragma unroll
                for (int u = 0; u < 8; ++u)
                    p[u] = (unsigned)__shfl_xor((int)kk[u], d, 64);
                #pragma unroll
                for (int u = 0; u < 8; ++u)
                    kk[u] = umn(kk[u], p[7 - u]);
                CE(0,4) CE(1,5) CE(2,6) CE(3,7)
                CE(0,2) CE(1,3) CE(4,6) CE(5,7)
                CE(0,1) CE(2,3) CE(4,5) CE(6,7)
            }

            if (m == 0) {
                uint4* dst = (uint4*)&blkTop[((size_t)grow * 64 + cblk2) * 8];
                uint4 lo4 = { kk[0], kk[1], kk[2], kk[3] };
                uint4 hi4 = { kk[4], kk[5], kk[6], kk[7] };
                dst[0] = lo4;
                dst[1] = hi4;
            }
        }
    }
#undef CE
}

// Phase 1b: merge 64 blocks x 8 keys per row -> top-16 candidates.
__global__ void merge_topk_kernel(const unsigned* __restrict__ blkTop,
                                  int* __restrict__ cand) {
    const int wv   = threadIdx.x >> 6;
    const int lane = threadIdx.x & 63;
    const int row  = blockIdx.x * 4 + wv;
    const uint4* base = (const uint4*)(blkTop + (size_t)row * 512);

    uint4 a = base[lane * 2];
    uint4 b = base[lane * 2 + 1];
    unsigned in[8] = { a.x, a.y, a.z, a.w, b.x, b.y, b.z, b.w };
    unsigned kk[8];
    #pragma unroll
    for (int j = 0; j < 8; ++j) {
        kk[j] = in[j];
        #pragma unroll
        for (int s = 7; s > 0; --s) {
            if (s <= j) {
                unsigned lo = umn(kk[s - 1], kk[s]);
                unsigned hi = kk[s - 1] < kk[s] ? kk[s] : kk[s - 1];
                kk[s - 1] = lo; kk[s] = hi;
            }
        }
    }

    unsigned sval = 0;
    #pragma unroll
    for (int s = 0; s < NCAND; ++s) {
        unsigned g = kk[0];
        #pragma unroll
        for (int d = 32; d; d >>= 1)
            g = umn(g, (unsigned)__shfl_xor((int)g, d, 64));
        bool pop = (kk[0] == g);
        #pragma unroll
        for (int u = 0; u < 7; ++u) kk[u] = pop ? kk[u + 1] : kk[u];
        kk[7] = pop ? 0xFFFFFFFFu : kk[7];
        sval = (lane == s) ? g : sval;
    }
    if (lane < NCAND)
        cand[(size_t)row * NCAND + lane] = (int)(sval & 0xFFFFu);
}

// Phase 2: exact numpy-fp32 replica rescore (selection logic unchanged since
// R4) + FULL k_hot row write (zeros + the 4 ones in one pass; replaces the
// 512 MB memset).
__global__ void rescore_kernel(const float* __restrict__ ze,
                               const float* __restrict__ cb,
                               const int* __restrict__ cand,
                               float* __restrict__ out_zq,
                               float* __restrict__ out_khot,
                               double* __restrict__ lossAcc) {
    __shared__ float zsh[4][DIM];
    const int wv = threadIdx.x >> 6;
    const int lane = threadIdx.x & 63;
    const int row = blockIdx.x * 4 + wv;

    {
        const float* zp = ze + (size_t)row * DIM + lane * 8;
        float4 v0 = *(const float4*)zp;
        float4 v1 = *(const float4*)(zp + 4);
        *(float4*)&zsh[wv][lane * 8]     = v0;
        *(float4*)&zsh[wv][lane * 8 + 4] = v1;
    }
    __syncthreads();

    // znorm, numpy-pairwise
    float racc = 0.0f;
    {
        const int b = (lane >> 3) & 3;
        const int j = lane & 7;
        const float* zr = &zsh[wv][128 * b + j];
        #pragma unroll
        for (int i = 0; i < 16; ++i) {
            float zk = zr[8 * i];
            float sq = zk * zk;
            asm volatile("" : "+v"(sq));   // block FMA contraction into the add
            racc = racc + sq;
        }
    }
    float t1 = racc + __shfl_xor(racc, 1, 64);
    float t2 = t1 + __shfl_xor(t1, 2, 64);
    float t3 = t2 + __shfl_xor(t2, 4, 64);
    float zn = (__shfl(t3, 0, 64) + __shfl(t3, 8, 64))
             + (__shfl(t3, 16, 64) + __shfl(t3, 24, 64));

    // candidate chains: KC=384 split, sequential FMA, single accumulator each
    float qv = 3.0e38f;
    int   idxv = 0x7fffffff;
    if (lane < NCAND) {
        idxv = cand[(size_t)row * NCAND + lane];
        const float* wp = cb + (size_t)idxv * DIM;
        const float* zz = zsh[wv];
        float acc1 = 0.0f;
        for (int k = 0; k < 384; k += 8) {
            float4 wa = *(const float4*)(wp + k);
            float4 wb = *(const float4*)(wp + k + 4);
            acc1 = __builtin_fmaf(zz[k + 0], wa.x, acc1);
            acc1 = __builtin_fmaf(zz[k + 1], wa.y, acc1);
            acc1 = __builtin_fmaf(zz[k + 2], wa.z, acc1);
            acc1 = __builtin_fmaf(zz[k + 3], wa.w, acc1);
            acc1 = __builtin_fmaf(zz[k + 4], wb.x, acc1);
            acc1 = __builtin_fmaf(zz[k + 5], wb.y, acc1);
            acc1 = __builtin_fmaf(zz[k + 6], wb.z, acc1);
            acc1 = __builtin_fmaf(zz[k + 7], wb.w, acc1);
        }
        float acc2 = 0.0f;
        for (int k = 384; k < 512; k += 8) {
            float4 wa = *(const float4*)(wp + k);
            float4 wb = *(const float4*)(wp + k + 4);
            acc2 = __builtin_fmaf(zz[k + 0], wa.x, acc2);
            acc2 = __builtin_fmaf(zz[k + 1], wa.y, acc2);
            acc2 = __builtin_fmaf(zz[k + 2], wa.z, acc2);
            acc2 = __builtin_fmaf(zz[k + 3], wa.w, acc2);
            acc2 = __builtin_fmaf(zz[k + 4], wb.x, acc2);
            acc2 = __builtin_fmaf(zz[k + 5], wb.y, acc2);
            acc2 = __builtin_fmaf(zz[k + 6], wb.z, acc2);
            acc2 = __builtin_fmaf(zz[k + 7], wb.w, acc2);
        }
        float Cv = acc1 + acc2;
        qv = zn - 2.0f * Cv;
    }

    float q[NCAND]; int id[NCAND];
    #pragma unroll
    for (int c = 0; c < NCAND; ++c) {
        q[c]  = __shfl(qv, c, 64);
        id[c] = __shfl(idxv, c, 64);
    }
    int selIdx[4];
    bool used[NCAND];
    #pragma unroll
    for (int c = 0; c < NCAND; ++c) used[c] = false;
    #pragma unroll
    for (int s = 0; s < 4; ++s) {
        float bq = 3.0e38f; int bi = 0x7fffffff; int bc = -1;
        #pragma unroll
        for (int c = 0; c < NCAND; ++c) {
            bool better = !used[c] && (q[c] < bq || (q[c] == bq && id[c] < bi));
            if (better) { bq = q[c]; bi = id[c]; bc = c; }
        }
        selIdx[s] = bi;
        #pragma unroll
        for (int c = 0; c < NCAND; ++c) used[c] = used[c] || (c == bc);
    }

    float zq[8] = { 0, 0, 0, 0, 0, 0, 0, 0 };
    #pragma unroll
    for (int s = 0; s < 4; ++s) {
        const float* wp = cb + (size_t)selIdx[s] * DIM + lane * 8;
        float4 w0 = *(const float4*)wp;
        float4 w1 = *(const float4*)(wp + 4);
        zq[0] += w0.x; zq[1] += w0.y; zq[2] += w0.z; zq[3] += w0.w;
        zq[4] += w1.x; zq[5] += w1.y; zq[6] += w1.z; zq[7] += w1.w;
    }

    float zf[8];
    {
        const float* zz = &zsh[wv][lane * 8];
        #pragma unroll
        for (int i = 0; i < 8; ++i) zf[i] = zz[i];
    }
    float o[8];
    double l = 0.0;
    #pragma unroll
    for (int i = 0; i < 8; ++i) {
        float zqf  = zq[i] * 0.25f;
        float diff = zqf - zf[i];
        o[i] = zf[i] + diff;
        double ld = (double)diff;
        l += ld * ld;
    }
    {
        float* op = out_zq + (size_t)row * DIM + lane * 8;
        float4 v0 = { o[0], o[1], o[2], o[3] };
        float4 v1 = { o[4], o[5], o[6], o[7] };
        *(float4*)op = v0;
        *(float4*)(op + 4) = v1;
    }
    #pragma unroll
    for (int mm = 32; mm; mm >>= 1) l += __shfl_xor(l, mm, 64);
    if (lane == 0) atomicAdd(lossAcc, l);

    // full k_hot row write: lane owns cols {j*256 + lane*4 + e}.
    // hot mask: col -> j = col>>8, e = col&3, owner lane = (col>>2)&63.
    unsigned hotm[4] = { 0u, 0u, 0u, 0u };
    #pragma unroll
    for (int s = 0; s < 4; ++s) {
        int si = selIdx[s];
        bool own = ((si >> 2) & 63) == lane;
        int jj = si >> 8;
        unsigned bit = 1u << (((jj & 7) << 2) | (si & 3));
        int word = jj >> 3;
        #pragma unroll
        for (int wd = 0; wd < 4; ++wd)
            hotm[wd] |= (own && word == wd) ? bit : 0u;
    }
    float* kp = out_khot + (size_t)row * N_EMB;
    #pragma unroll
    for (int j = 0; j < 32; ++j) {
        unsigned bits = (hotm[j >> 3] >> ((j & 7) * 4)) & 0xFu;
        float4 v;
        v.x = (bits & 1u) ? 1.0f : 0.0f;
        v.y = (bits & 2u) ? 1.0f : 0.0f;
        v.z = (bits & 4u) ? 1.0f : 0.0f;
        v.w = (bits & 8u) ? 1.0f : 0.0f;
        *(float4*)(kp + j * 256 + lane * 4) = v;
    }
}

__global__ void finalize_kernel(const double* __restrict__ lossAcc,
                                float* __restrict__ out_loss) {
    if (threadIdx.x == 0 && blockIdx.x == 0)
        out_loss[0] = (float)(lossAcc[0] * (1.25 / ((double)N_ROWS * (double)DIM)));
}

extern "C" void kernel_launch(void* const* d_in, const int* in_sizes, int n_in,
                              void* d_out, int out_size, void* d_ws, size_t ws_size,
                              hipStream_t stream) {
    (void)in_sizes; (void)n_in; (void)out_size; (void)ws_size;
    const float* ze = (const float*)d_in[0];
    const float* cb = (const float*)d_in[1];

    float* out      = (float*)d_out;
    float* out_zq   = out;                                   // [16384, 512]
    float* out_loss = out + (size_t)N_ROWS * DIM;            // [1]
    float* out_khot = out_loss + 1;                          // [16384, 8192]

    double* lossAcc = (double*)d_ws;
    int*    cand    = (int*)((char*)d_ws + 16);

    // scratch inside k_hot region, 16B-aligned, consumed before rescore
    char* base = (char*)d_out;
    unsigned*       blkTop = (unsigned*)(base + 33554448);                  // khot + 12 B
    unsigned short* ze16   = (unsigned short*)(base + 33554448 + 33554432); // + 32 MB
    unsigned short* cb16   = ze16 + (size_t)N_ROWS * DIM;

    hipMemsetAsync(lossAcc, 0, 16, stream);

    convert_bf16_kernel<<<6144, 256, 0, stream>>>(ze, cb, ze16, cb16);
    score_gemm_topk_kernel<<<2048, 512, 0, stream>>>(ze16, cb16, blkTop);
    merge_topk_kernel<<<N_ROWS / 4, 256, 0, stream>>>(blkTop, cand);
    rescore_kernel<<<N_ROWS / 4, 256, 0, stream>>>(ze, cb, cand, out_zq, out_khot, lossAcc);
    finalize_kernel<<<1, 64, 0, stream>>>(lossAcc, out_loss);
}

// Round 7
// 968.323 us; speedup vs baseline: 1.0614x; 1.0586x over previous
//
#include <hip/hip_runtime.h>

#define N_ROWS 16384
#define N_EMB  8192
#define DIM    512
#define NCAND  16

#define GAS __attribute__((address_space(1)))
#define LAS __attribute__((address_space(3)))

// ---------------------------------------------------------------------------
// ws layout:
//   [0]    double lossAcc (16 B, zeroed)
//   [16]   int cand[N_ROWS * NCAND]   (1 MB)
// k_hot region (512 MB at d_out + 33554436 B) is scratch BEFORE rescore:
//   +12 B          : blkTop u32[N_ROWS*64*8]   (32 MB) per-block top-8 keys
//   +12+32 MB      : ze_bf16 u16[N_ROWS*DIM]   (16.8 MB)
//   then           : cb_bf16 u16[N_EMB*DIM]    ( 8.4 MB)
// Consumed by gemm/merge (stream-ordered before rescore overwrites k_hot).
// ---------------------------------------------------------------------------

typedef short  bhalf8  __attribute__((ext_vector_type(8)));
typedef float  floatx4 __attribute__((ext_vector_type(4)));

__device__ __forceinline__ unsigned short f2b(float f) {
    unsigned u = __builtin_bit_cast(unsigned, f);
    unsigned r = (u + 0x7fffu + ((u >> 16) & 1u)) >> 16;   // RNE
    return (unsigned short)r;
}
__device__ __forceinline__ unsigned pk2(float a, float b) {
    return (unsigned)f2b(a) | ((unsigned)f2b(b) << 16);
}
// sortable key: ascending u32 == ascending (score, col); lower col wins ties
__device__ __forceinline__ unsigned mkkey(float s, int col) {
    unsigned short b = f2b(s);
    unsigned short ts = (unsigned short)(b ^ ((b & 0x8000u) ? 0xFFFFu : 0x8000u));
    return ((unsigned)ts << 16) | (unsigned)col;
}
__device__ __forceinline__ unsigned umn(unsigned a, unsigned b) { return a < b ? a : b; }

// DPP lane permutations (VALU pipe, no LDS/ds_bpermute, no lgkm wait):
//   xor1 = quad_perm [1,0,3,2] = 0xB1 ; xor2 = quad_perm [2,3,0,1] = 0x4E ;
//   xor8 = ROW_ROR:8 (0x128): (l&15)+8 mod 16 == (l&15)^8 for all lanes.
// All are exact within each 16-lane group (our groups are lane&15).
__device__ __forceinline__ unsigned dpp_xor1(unsigned v) {
    return (unsigned)__builtin_amdgcn_update_dpp(0, (int)v, 0xB1, 0xF, 0xF, true);
}
__device__ __forceinline__ unsigned dpp_xor2(unsigned v) {
    return (unsigned)__builtin_amdgcn_update_dpp(0, (int)v, 0x4E, 0xF, 0xF, true);
}
__device__ __forceinline__ unsigned dpp_xor8(unsigned v) {
    return (unsigned)__builtin_amdgcn_update_dpp(0, (int)v, 0x128, 0xF, 0xF, true);
}

// fp32 -> bf16 one-time conversion of both inputs (8 elements/thread).
__global__ void convert_bf16_kernel(const float* __restrict__ ze,
                                    const float* __restrict__ cb,
                                    unsigned short* __restrict__ ze16,
                                    unsigned short* __restrict__ cb16) {
    size_t id = (size_t)blockIdx.x * 256 + threadIdx.x;
    const size_t nze = (size_t)N_ROWS * DIM / 8;
    const float* src;
    unsigned short* dst;
    size_t off;
    if (id < nze) { src = ze; dst = ze16; off = id * 8; }
    else          { src = cb; dst = cb16; off = (id - nze) * 8; }
    float4 a = *(const float4*)(src + off);
    float4 b = *(const float4*)(src + off + 4);
    uint4 u = { pk2(a.x, a.y), pk2(a.z, a.w), pk2(b.x, b.y), pk2(b.z, b.w) };
    *(uint4*)(dst + off) = u;
}

// Phase 1a: bf16 MFMA GEMM fused with per-block per-row top-8.
// R15 = R12 core verbatim (m97 2-phase 128x128, 5 blk/CU, XCD swizzle --
// best measured; 8-phase 256^2 regressed twice: 1-block/CU exposes the
// epilogue/prologue with nothing co-resident to overlap) with the epilogue
// cross-lane TRANSPORT rewritten:
//   - __shfl_xor (= ds_bpermute, LDS pipe, ~26+ cyc dependent latency) is
//     replaced by DPP moves for merge levels d=1,2,8 (VALU pipe, ~2-4 cyc).
//     Only d=4 (no DPP encoding) remains a shfl. 256 -> 64 ds ops/wave.
//   - final bitonic clean skipped: after the d=8 min step each lane holds
//     the top-8 MULTISET (bitonic order). blkTop is scratch read only by
//     merge_topk, which insertion-sorts per-lane -> order-independent ->
//     cand and all outputs bit-identical.
__launch_bounds__(256, 5)
__global__ void score_gemm_topk_kernel(const unsigned short* __restrict__ ze16,
                                       const unsigned short* __restrict__ cb16,
                                       unsigned* __restrict__ blkTop) {
    __shared__ unsigned short Amm[128 * 64];   // 16 KB
    __shared__ unsigned short Bmm[128 * 64];   // 16 KB

    const int t    = threadIdx.x;
    const int lane = t & 63;
    const int w    = t >> 6;

    // XCD-aware bijective decode (8 XCDs, round-robin dispatch on bid&7):
    // each XCD owns 8 consecutive col-tiles (1 MB B-slice, L2-resident) and
    // sweeps row-tiles with its col-tiles innermost.
    const int bid   = blockIdx.x;              // 0..8191
    const int xcd   = bid & 7;
    const int chunk = bid >> 3;                // 0..1023
    const int cblk  = xcd * 8 + (chunk & 7);   // col-tile 0..63
    const int rblk  = chunk >> 3;              // row-tile 0..127
    const int rowBase = rblk * 128;
    const int colBase = cblk * 128;

    const int m = lane & 15;
    const int q = lane >> 4;

    floatx4 acc[2][8];
    #pragma unroll
    for (int i = 0; i < 2; ++i)
        #pragma unroll
        for (int j = 0; j < 8; ++j)
            acc[i][j] = (floatx4){0.0f, 0.0f, 0.0f, 0.0f};

    // staging: call k covers tile rows k*32 + (t>>3); phys chunk t&7 holds
    // global chunk (t&7) ^ ((t>>3)&7)
    const int tr = t >> 3;
    const int cg = (t & 7) ^ (tr & 7);
    const unsigned short* pa = ze16 + (size_t)(rowBase + tr) * DIM + cg * 8;
    const unsigned short* pb = cb16 + (size_t)(colBase + tr) * DIM + cg * 8;

    // frag chunk offsets (elements): logical chunk h*4+q, row-swizzle m&7
    const int ch0 = ((0 * 4 + q) ^ (m & 7)) * 8;
    const int ch1 = ((1 * 4 + q) ^ (m & 7)) * 8;

    for (int k0 = 0; k0 < DIM; k0 += 64) {
        __syncthreads();
        #pragma unroll
        for (int k = 0; k < 4; ++k)
            __builtin_amdgcn_global_load_lds((const GAS void*)(pa + (size_t)k * 32 * DIM + k0),
                                             (LAS void*)(Amm + (k * 256 + w * 64) * 8), 16, 0, 0);
        #pragma unroll
        for (int k = 0; k < 4; ++k)
            __builtin_amdgcn_global_load_lds((const GAS void*)(pb + (size_t)k * 32 * DIM + k0),
                                             (LAS void*)(Bmm + (k * 256 + w * 64) * 8), 16, 0, 0);
        __syncthreads();

        #pragma unroll
        for (int h = 0; h < 2; ++h) {
            const int ch = h ? ch1 : ch0;
            bhalf8 af0 = *(bhalf8*)&Amm[(w * 32 + m) * 64 + ch];
            bhalf8 af1 = *(bhalf8*)&Amm[(w * 32 + 16 + m) * 64 + ch];
            #pragma unroll
            for (int j = 0; j < 8; ++j) {
                bhalf8 bf = *(bhalf8*)&Bmm[(j * 16 + m) * 64 + ch];
                acc[0][j] = __builtin_amdgcn_mfma_f32_16x16x32_bf16(af0, bf, acc[0][j], 0, 0, 0);
                acc[1][j] = __builtin_amdgcn_mfma_f32_16x16x32_bf16(af1, bf, acc[1][j], 0, 0, 0);
            }
        }
    }

    // Epilogue: per (i,reg), 16-lane group holds 128 keys (8/lane); produce
    // the top-8 multiset (levels 1-3 sorted merges, level 4 min-only).
#define CE(x, y) { unsigned _lo = umn(kk[x], kk[y]);                         \
                   unsigned _hi = kk[x] < kk[y] ? kk[y] : kk[x];             \
                   kk[x] = _lo; kk[y] = _hi; }
    #pragma unroll
    for (int i = 0; i < 2; ++i) {
        #pragma unroll
        for (int reg = 0; reg < 4; ++reg) {
            const int grow = rowBase + w * 32 + i * 16 + q * 4 + reg;
            unsigned kk[8];
            #pragma unroll
            for (int j = 0; j < 8; ++j)
                kk[j] = mkkey(-acc[i][j][reg], colBase + j * 16 + m);

            // Batcher odd-even mergesort, 8 elements, 19 CE -> ascending
            CE(0,1) CE(2,3) CE(4,5) CE(6,7)
            CE(0,2) CE(1,3) CE(4,6) CE(5,7)
            CE(1,2) CE(5,6)
            CE(0,4) CE(1,5) CE(2,6) CE(3,7)
            CE(2,4) CE(3,5)
            CE(1,2) CE(3,4) CE(5,6)

            unsigned p[8];
            // level d=1 (DPP quad_perm) + clean
            #pragma unroll
            for (int u = 0; u < 8; ++u) p[u] = dpp_xor1(kk[u]);
            #pragma unroll
            for (int u = 0; u < 8; ++u) kk[u] = umn(kk[u], p[7 - u]);
            CE(0,4) CE(1,5) CE(2,6) CE(3,7)
            CE(0,2) CE(1,3) CE(4,6) CE(5,7)
            CE(0,1) CE(2,3) CE(4,5) CE(6,7)
            // level d=2 (DPP quad_perm) + clean
            #pragma unroll
            for (int u = 0; u < 8; ++u) p[u] = dpp_xor2(kk[u]);
            #pragma unroll
            for (int u = 0; u < 8; ++u) kk[u] = umn(kk[u], p[7 - u]);
            CE(0,4) CE(1,5) CE(2,6) CE(3,7)
            CE(0,2) CE(1,3) CE(4,6) CE(5,7)
            CE(0,1) CE(2,3) CE(4,5) CE(6,7)
            // level d=4 (no DPP encoding -> shfl) + clean
            #pragma unroll
            for (int u = 0; u < 8; ++u)
                p[u] = (unsigned)__shfl_xor((int)kk[u], 4, 64);
            #pragma unroll
            for (int u = 0; u < 8; ++u) kk[u] = umn(kk[u], p[7 - u]);
            CE(0,4) CE(1,5) CE(2,6) CE(3,7)
            CE(0,2) CE(1,3) CE(4,6) CE(5,7)
            CE(0,1) CE(2,3) CE(4,5) CE(6,7)
            // level d=8 (DPP row_ror:8), min only -- bitonic result holds
            // the exact top-8 multiset; merge_topk is order-independent.
            #pragma unroll
            for (int u = 0; u < 8; ++u) p[u] = dpp_xor8(kk[u]);
            #pragma unroll
            for (int u = 0; u < 8; ++u) kk[u] = umn(kk[u], p[7 - u]);

            if (m == 0) {
                uint4* dst = (uint4*)&blkTop[((size_t)grow * 64 + cblk) * 8];
                uint4 lo4 = { kk[0], kk[1], kk[2], kk[3] };
                uint4 hi4 = { kk[4], kk[5], kk[6], kk[7] };
                dst[0] = lo4;
                dst[1] = hi4;
            }
        }
    }
#undef CE
}

// Phase 1b: merge 64 blocks x 8 keys per row -> top-16 candidates.
// (Input chunk order is irrelevant: per-lane insertion sort + extract-min.)
__global__ void merge_topk_kernel(const unsigned* __restrict__ blkTop,
                                  int* __restrict__ cand) {
    const int wv   = threadIdx.x >> 6;
    const int lane = threadIdx.x & 63;
    const int row  = blockIdx.x * 4 + wv;
    const uint4* base = (const uint4*)(blkTop + (size_t)row * 512);

    uint4 a = base[lane * 2];
    uint4 b = base[lane * 2 + 1];
    unsigned in[8] = { a.x, a.y, a.z, a.w, b.x, b.y, b.z, b.w };
    unsigned kk[8];
    #pragma unroll
    for (int j = 0; j < 8; ++j) {
        kk[j] = in[j];
        #pragma unroll
        for (int s = 7; s > 0; --s) {
            if (s <= j) {
                unsigned lo = umn(kk[s - 1], kk[s]);
                unsigned hi = kk[s - 1] < kk[s] ? kk[s] : kk[s - 1];
                kk[s - 1] = lo; kk[s] = hi;
            }
        }
    }

    unsigned sval = 0;
    #pragma unroll
    for (int s = 0; s < NCAND; ++s) {
        unsigned g = kk[0];
        #pragma unroll
        for (int d = 32; d; d >>= 1)
            g = umn(g, (unsigned)__shfl_xor((int)g, d, 64));
        bool pop = (kk[0] == g);
        #pragma unroll
        for (int u = 0; u < 7; ++u) kk[u] = pop ? kk[u + 1] : kk[u];
        kk[7] = pop ? 0xFFFFFFFFu : kk[7];
        sval = (lane == s) ? g : sval;
    }
    if (lane < NCAND)
        cand[(size_t)row * NCAND + lane] = (int)(sval & 0xFFFFu);
}

// Phase 2: exact numpy-fp32 replica rescore (selection logic unchanged since
// R4) + FULL k_hot row write (zeros + the 4 ones in one pass; replaces the
// 512 MB memset).
__global__ void rescore_kernel(const float* __restrict__ ze,
                               const float* __restrict__ cb,
                               const int* __restrict__ cand,
                               float* __restrict__ out_zq,
                               float* __restrict__ out_khot,
                               double* __restrict__ lossAcc) {
    __shared__ float zsh[4][DIM];
    const int wv = threadIdx.x >> 6;
    const int lane = threadIdx.x & 63;
    const int row = blockIdx.x * 4 + wv;

    {
        const float* zp = ze + (size_t)row * DIM + lane * 8;
        float4 v0 = *(const float4*)zp;
        float4 v1 = *(const float4*)(zp + 4);
        *(float4*)&zsh[wv][lane * 8]     = v0;
        *(float4*)&zsh[wv][lane * 8 + 4] = v1;
    }
    __syncthreads();

    // znorm, numpy-pairwise
    float racc = 0.0f;
    {
        const int b = (lane >> 3) & 3;
        const int j = lane & 7;
        const float* zr = &zsh[wv][128 * b + j];
        #pragma unroll
        for (int i = 0; i < 16; ++i) {
            float zk = zr[8 * i];
            float sq = zk * zk;
            asm volatile("" : "+v"(sq));   // block FMA contraction into the add
            racc = racc + sq;
        }
    }
    float t1 = racc + __shfl_xor(racc, 1, 64);
    float t2 = t1 + __shfl_xor(t1, 2, 64);
    float t3 = t2 + __shfl_xor(t2, 4, 64);
    float zn = (__shfl(t3, 0, 64) + __shfl(t3, 8, 64))
             + (__shfl(t3, 16, 64) + __shfl(t3, 24, 64));

    // candidate chains: KC=384 split, sequential FMA, single accumulator each
    float qv = 3.0e38f;
    int   idxv = 0x7fffffff;
    if (lane < NCAND) {
        idxv = cand[(size_t)row * NCAND + lane];
        const float* wp = cb + (size_t)idxv * DIM;
        const float* zz = zsh[wv];
        float acc1 = 0.0f;
        for (int k = 0; k < 384; k += 8) {
            float4 wa = *(const float4*)(wp + k);
            float4 wb = *(const float4*)(wp + k + 4);
            acc1 = __builtin_fmaf(zz[k + 0], wa.x, acc1);
            acc1 = __builtin_fmaf(zz[k + 1], wa.y, acc1);
            acc1 = __builtin_fmaf(zz[k + 2], wa.z, acc1);
            acc1 = __builtin_fmaf(zz[k + 3], wa.w, acc1);
            acc1 = __builtin_fmaf(zz[k + 4], wb.x, acc1);
            acc1 = __builtin_fmaf(zz[k + 5], wb.y, acc1);
            acc1 = __builtin_fmaf(zz[k + 6], wb.z, acc1);
            acc1 = __builtin_fmaf(zz[k + 7], wb.w, acc1);
        }
        float acc2 = 0.0f;
        for (int k = 384; k < 512; k += 8) {
            float4 wa = *(const float4*)(wp + k);
            float4 wb = *(const float4*)(wp + k + 4);
            acc2 = __builtin_fmaf(zz[k + 0], wa.x, acc2);
            acc2 = __builtin_fmaf(zz[k + 1], wa.y, acc2);
            acc2 = __builtin_fmaf(zz[k + 2], wa.z, acc2);
            acc2 = __builtin_fmaf(zz[k + 3], wa.w, acc2);
            acc2 = __builtin_fmaf(zz[k + 4], wb.x, acc2);
            acc2 = __builtin_fmaf(zz[k + 5], wb.y, acc2);
            acc2 = __builtin_fmaf(zz[k + 6], wb.z, acc2);
            acc2 = __builtin_fmaf(zz[k + 7], wb.w, acc2);
        }
        float Cv = acc1 + acc2;
        qv = zn - 2.0f * Cv;
    }

    float q[NCAND]; int id[NCAND];
    #pragma unroll
    for (int c = 0; c < NCAND; ++c) {
        q[c]  = __shfl(qv, c, 64);
        id[c] = __shfl(idxv, c, 64);
    }
    int selIdx[4];
    bool used[NCAND];
    #pragma unroll
    for (int c = 0; c < NCAND; ++c) used[c] = false;
    #pragma unroll
    for (int s = 0; s < 4; ++s) {
        float bq = 3.0e38f; int bi = 0x7fffffff; int bc = -1;
        #pragma unroll
        for (int c = 0; c < NCAND; ++c) {
            bool better = !used[c] && (q[c] < bq || (q[c] == bq && id[c] < bi));
            if (better) { bq = q[c]; bi = id[c]; bc = c; }
        }
        selIdx[s] = bi;
        #pragma unroll
        for (int c = 0; c < NCAND; ++c) used[c] = used[c] || (c == bc);
    }

    float zq[8] = { 0, 0, 0, 0, 0, 0, 0, 0 };
    #pragma unroll
    for (int s = 0; s < 4; ++s) {
        const float* wp = cb + (size_t)selIdx[s] * DIM + lane * 8;
        float4 w0 = *(const float4*)wp;
        float4 w1 = *(const float4*)(wp + 4);
        zq[0] += w0.x; zq[1] += w0.y; zq[2] += w0.z; zq[3] += w0.w;
        zq[4] += w1.x; zq[5] += w1.y; zq[6] += w1.z; zq[7] += w1.w;
    }

    float zf[8];
    {
        const float* zz = &zsh[wv][lane * 8];
        #pragma unroll
        for (int i = 0; i < 8; ++i) zf[i] = zz[i];
    }
    float o[8];
    double l = 0.0;
    #pragma unroll
    for (int i = 0; i < 8; ++i) {
        float zqf  = zq[i] * 0.25f;
        float diff = zqf - zf[i];
        o[i] = zf[i] + diff;
        double ld = (double)diff;
        l += ld * ld;
    }
    {
        float* op = out_zq + (size_t)row * DIM + lane * 8;
        float4 v0 = { o[0], o[1], o[2], o[3] };
        float4 v1 = { o[4], o[5], o[6], o[7] };
        *(float4*)op = v0;
        *(float4*)(op + 4) = v1;
    }
    #pragma unroll
    for (int mm = 32; mm; mm >>= 1) l += __shfl_xor(l, mm, 64);
    if (lane == 0) atomicAdd(lossAcc, l);

    // full k_hot row write: lane owns cols {j*256 + lane*4 + e}.
    // hot mask: col -> j = col>>8, e = col&3, owner lane = (col>>2)&63.
    unsigned hotm[4] = { 0u, 0u, 0u, 0u };
    #pragma unroll
    for (int s = 0; s < 4; ++s) {
        int si = selIdx[s];
        bool own = ((si >> 2) & 63) == lane;
        int jj = si >> 8;
        unsigned bit = 1u << (((jj & 7) << 2) | (si & 3));
        int word = jj >> 3;
        #pragma unroll
        for (int wd = 0; wd < 4; ++wd)
            hotm[wd] |= (own && word == wd) ? bit : 0u;
    }
    float* kp = out_khot + (size_t)row * N_EMB;
    #pragma unroll
    for (int j = 0; j < 32; ++j) {
        unsigned bits = (hotm[j >> 3] >> ((j & 7) * 4)) & 0xFu;
        float4 v;
        v.x = (bits & 1u) ? 1.0f : 0.0f;
        v.y = (bits & 2u) ? 1.0f : 0.0f;
        v.z = (bits & 4u) ? 1.0f : 0.0f;
        v.w = (bits & 8u) ? 1.0f : 0.0f;
        *(float4*)(kp + j * 256 + lane * 4) = v;
    }
}

__global__ void finalize_kernel(const double* __restrict__ lossAcc,
                                float* __restrict__ out_loss) {
    if (threadIdx.x == 0 && blockIdx.x == 0)
        out_loss[0] = (float)(lossAcc[0] * (1.25 / ((double)N_ROWS * (double)DIM)));
}

extern "C" void kernel_launch(void* const* d_in, const int* in_sizes, int n_in,
                              void* d_out, int out_size, void* d_ws, size_t ws_size,
                              hipStream_t stream) {
    (void)in_sizes; (void)n_in; (void)out_size; (void)ws_size;
    const float* ze = (const float*)d_in[0];
    const float* cb = (const float*)d_in[1];

    float* out      = (float*)d_out;
    float* out_zq   = out;                                   // [16384, 512]
    float* out_loss = out + (size_t)N_ROWS * DIM;            // [1]
    float* out_khot = out_loss + 1;                          // [16384, 8192]

    double* lossAcc = (double*)d_ws;
    int*    cand    = (int*)((char*)d_ws + 16);

    // scratch inside k_hot region, 16B-aligned, consumed before rescore
    char* base = (char*)d_out;
    unsigned*       blkTop = (unsigned*)(base + 33554448);                  // khot + 12 B
    unsigned short* ze16   = (unsigned short*)(base + 33554448 + 33554432); // + 32 MB
    unsigned short* cb16   = ze16 + (size_t)N_ROWS * DIM;

    hipMemsetAsync(lossAcc, 0, 16, stream);

    convert_bf16_kernel<<<6144, 256, 0, stream>>>(ze, cb, ze16, cb16);
    score_gemm_topk_kernel<<<8192, 256, 0, stream>>>(ze16, cb16, blkTop);
    merge_topk_kernel<<<N_ROWS / 4, 256, 0, stream>>>(blkTop, cand);
    rescore_kernel<<<N_ROWS / 4, 256, 0, stream>>>(ze, cb, cand, out_zq, out_khot, lossAcc);
    finalize_kernel<<<1, 64, 0, stream>>>(lossAcc, out_loss);
}

// Round 8
// 964.977 us; speedup vs baseline: 1.0650x; 1.0035x over previous
//
#include <hip/hip_runtime.h>

#define N_ROWS 16384
#define N_EMB  8192
#define DIM    512
#define NCAND  16

#define GAS __attribute__((address_space(1)))
#define LAS __attribute__((address_space(3)))

// ---------------------------------------------------------------------------
// ws layout:
//   [0]    double lossAcc (16 B, zeroed)
//   [16]   int cand[N_ROWS * NCAND]   (1 MB)
// k_hot region (512 MB at d_out + 33554436 B) is scratch BEFORE rescore:
//   +12 B          : blkTop u32[N_ROWS*64*8]   (32 MB) per-block top-8 keys
//   +12+32 MB      : ze_bf16 u16[N_ROWS*DIM]   (16.8 MB)
//   then           : cb_bf16 u16[N_EMB*DIM]    ( 8.4 MB)
// Consumed by gemm/merge (stream-ordered before rescore overwrites k_hot).
// ---------------------------------------------------------------------------

typedef short  bhalf8  __attribute__((ext_vector_type(8)));
typedef float  floatx4 __attribute__((ext_vector_type(4)));

__device__ __forceinline__ unsigned short f2b(float f) {
    unsigned u = __builtin_bit_cast(unsigned, f);
    unsigned r = (u + 0x7fffu + ((u >> 16) & 1u)) >> 16;   // RNE
    return (unsigned short)r;
}
__device__ __forceinline__ unsigned pk2(float a, float b) {
    return (unsigned)f2b(a) | ((unsigned)f2b(b) << 16);
}
// sortable key: ascending u32 == ascending (score, col); lower col wins ties
__device__ __forceinline__ unsigned mkkey(float s, int col) {
    unsigned short b = f2b(s);
    unsigned short ts = (unsigned short)(b ^ ((b & 0x8000u) ? 0xFFFFu : 0x8000u));
    return ((unsigned)ts << 16) | (unsigned)col;
}
__device__ __forceinline__ unsigned umn(unsigned a, unsigned b) { return a < b ? a : b; }

// DPP lane permutations (VALU pipe, no LDS/ds_bpermute, no lgkm wait):
//   xor1 = quad_perm [1,0,3,2] = 0xB1 ; xor2 = quad_perm [2,3,0,1] = 0x4E ;
//   xor8 = ROW_ROR:8 (0x128): within a 16-row, (l+8) mod 16 == l^8.
//   xor4 = xor7 o xor3: quad_perm [3,2,1,0] (0x1B, l^3) then
//          row_half_mirror (0x141, l^7): v[(l^7)^3] = v[l^4]. 2 VALU ops.
// All exact within each 16-lane row (R15 proved xor1/2/8 via absmax 0.0).
__device__ __forceinline__ unsigned dpp_xor1(unsigned v) {
    return (unsigned)__builtin_amdgcn_update_dpp(0, (int)v, 0xB1, 0xF, 0xF, true);
}
__device__ __forceinline__ unsigned dpp_xor2(unsigned v) {
    return (unsigned)__builtin_amdgcn_update_dpp(0, (int)v, 0x4E, 0xF, 0xF, true);
}
__device__ __forceinline__ unsigned dpp_xor8(unsigned v) {
    return (unsigned)__builtin_amdgcn_update_dpp(0, (int)v, 0x128, 0xF, 0xF, true);
}
__device__ __forceinline__ unsigned dpp_xor4(unsigned v) {
    unsigned t = (unsigned)__builtin_amdgcn_update_dpp(0, (int)v, 0x1B, 0xF, 0xF, true);
    return (unsigned)__builtin_amdgcn_update_dpp(0, (int)t, 0x141, 0xF, 0xF, true);
}

// fp32 -> bf16 one-time conversion of both inputs (8 elements/thread).
__global__ void convert_bf16_kernel(const float* __restrict__ ze,
                                    const float* __restrict__ cb,
                                    unsigned short* __restrict__ ze16,
                                    unsigned short* __restrict__ cb16) {
    size_t id = (size_t)blockIdx.x * 256 + threadIdx.x;
    const size_t nze = (size_t)N_ROWS * DIM / 8;
    const float* src;
    unsigned short* dst;
    size_t off;
    if (id < nze) { src = ze; dst = ze16; off = id * 8; }
    else          { src = cb; dst = cb16; off = (id - nze) * 8; }
    float4 a = *(const float4*)(src + off);
    float4 b = *(const float4*)(src + off + 4);
    uint4 u = { pk2(a.x, a.y), pk2(a.z, a.w), pk2(b.x, b.y), pk2(b.z, b.w) };
    *(uint4*)(dst + off) = u;
}

// Phase 1a: bf16 MFMA GEMM fused with per-block per-row top-8.
// R16 = R15 (m97 2-phase 128x128, XCD swizzle, DPP epilogue -- confirmed
// -30.6us) with the LAST epilogue DS ops removed: the d=4 merge level now
// uses the two-DPP xor4 composite instead of __shfl_xor (ds_bpermute).
// Epilogue is now 100% VALU transport. Same permutation -> same bytes.
__launch_bounds__(256, 5)
__global__ void score_gemm_topk_kernel(const unsigned short* __restrict__ ze16,
                                       const unsigned short* __restrict__ cb16,
                                       unsigned* __restrict__ blkTop) {
    __shared__ unsigned short Amm[128 * 64];   // 16 KB
    __shared__ unsigned short Bmm[128 * 64];   // 16 KB

    const int t    = threadIdx.x;
    const int lane = t & 63;
    const int w    = t >> 6;

    // XCD-aware bijective decode (8 XCDs, round-robin dispatch on bid&7):
    // each XCD owns 8 consecutive col-tiles (1 MB B-slice, L2-resident) and
    // sweeps row-tiles with its col-tiles innermost.
    const int bid   = blockIdx.x;              // 0..8191
    const int xcd   = bid & 7;
    const int chunk = bid >> 3;                // 0..1023
    const int cblk  = xcd * 8 + (chunk & 7);   // col-tile 0..63
    const int rblk  = chunk >> 3;              // row-tile 0..127
    const int rowBase = rblk * 128;
    const int colBase = cblk * 128;

    const int m = lane & 15;
    const int q = lane >> 4;

    floatx4 acc[2][8];
    #pragma unroll
    for (int i = 0; i < 2; ++i)
        #pragma unroll
        for (int j = 0; j < 8; ++j)
            acc[i][j] = (floatx4){0.0f, 0.0f, 0.0f, 0.0f};

    // staging: call k covers tile rows k*32 + (t>>3); phys chunk t&7 holds
    // global chunk (t&7) ^ ((t>>3)&7)
    const int tr = t >> 3;
    const int cg = (t & 7) ^ (tr & 7);
    const unsigned short* pa = ze16 + (size_t)(rowBase + tr) * DIM + cg * 8;
    const unsigned short* pb = cb16 + (size_t)(colBase + tr) * DIM + cg * 8;

    // frag chunk offsets (elements): logical chunk h*4+q, row-swizzle m&7
    const int ch0 = ((0 * 4 + q) ^ (m & 7)) * 8;
    const int ch1 = ((1 * 4 + q) ^ (m & 7)) * 8;

    for (int k0 = 0; k0 < DIM; k0 += 64) {
        __syncthreads();
        #pragma unroll
        for (int k = 0; k < 4; ++k)
            __builtin_amdgcn_global_load_lds((const GAS void*)(pa + (size_t)k * 32 * DIM + k0),
                                             (LAS void*)(Amm + (k * 256 + w * 64) * 8), 16, 0, 0);
        #pragma unroll
        for (int k = 0; k < 4; ++k)
            __builtin_amdgcn_global_load_lds((const GAS void*)(pb + (size_t)k * 32 * DIM + k0),
                                             (LAS void*)(Bmm + (k * 256 + w * 64) * 8), 16, 0, 0);
        __syncthreads();

        #pragma unroll
        for (int h = 0; h < 2; ++h) {
            const int ch = h ? ch1 : ch0;
            bhalf8 af0 = *(bhalf8*)&Amm[(w * 32 + m) * 64 + ch];
            bhalf8 af1 = *(bhalf8*)&Amm[(w * 32 + 16 + m) * 64 + ch];
            #pragma unroll
            for (int j = 0; j < 8; ++j) {
                bhalf8 bf = *(bhalf8*)&Bmm[(j * 16 + m) * 64 + ch];
                acc[0][j] = __builtin_amdgcn_mfma_f32_16x16x32_bf16(af0, bf, acc[0][j], 0, 0, 0);
                acc[1][j] = __builtin_amdgcn_mfma_f32_16x16x32_bf16(af1, bf, acc[1][j], 0, 0, 0);
            }
        }
    }

    // Epilogue: per (i,reg), 16-lane group holds 128 keys (8/lane); produce
    // the top-8 multiset (levels 1-3 sorted merges, level 4 min-only).
    // All cross-lane transport is DPP (VALU) -- zero DS ops.
#define CE(x, y) { unsigned _lo = umn(kk[x], kk[y]);                         \
                   unsigned _hi = kk[x] < kk[y] ? kk[y] : kk[x];             \
                   kk[x] = _lo; kk[y] = _hi; }
    #pragma unroll
    for (int i = 0; i < 2; ++i) {
        #pragma unroll
        for (int reg = 0; reg < 4; ++reg) {
            const int grow = rowBase + w * 32 + i * 16 + q * 4 + reg;
            unsigned kk[8];
            #pragma unroll
            for (int j = 0; j < 8; ++j)
                kk[j] = mkkey(-acc[i][j][reg], colBase + j * 16 + m);

            // Batcher odd-even mergesort, 8 elements, 19 CE -> ascending
            CE(0,1) CE(2,3) CE(4,5) CE(6,7)
            CE(0,2) CE(1,3) CE(4,6) CE(5,7)
            CE(1,2) CE(5,6)
            CE(0,4) CE(1,5) CE(2,6) CE(3,7)
            CE(2,4) CE(3,5)
            CE(1,2) CE(3,4) CE(5,6)

            unsigned p[8];
            // level d=1 (DPP quad_perm) + clean
            #pragma unroll
            for (int u = 0; u < 8; ++u) p[u] = dpp_xor1(kk[u]);
            #pragma unroll
            for (int u = 0; u < 8; ++u) kk[u] = umn(kk[u], p[7 - u]);
            CE(0,4) CE(1,5) CE(2,6) CE(3,7)
            CE(0,2) CE(1,3) CE(4,6) CE(5,7)
            CE(0,1) CE(2,3) CE(4,5) CE(6,7)
            // level d=2 (DPP quad_perm) + clean
            #pragma unroll
            for (int u = 0; u < 8; ++u) p[u] = dpp_xor2(kk[u]);
            #pragma unroll
            for (int u = 0; u < 8; ++u) kk[u] = umn(kk[u], p[7 - u]);
            CE(0,4) CE(1,5) CE(2,6) CE(3,7)
            CE(0,2) CE(1,3) CE(4,6) CE(5,7)
            CE(0,1) CE(2,3) CE(4,5) CE(6,7)
            // level d=4 (two-DPP xor4 composite) + clean
            #pragma unroll
            for (int u = 0; u < 8; ++u) p[u] = dpp_xor4(kk[u]);
            #pragma unroll
            for (int u = 0; u < 8; ++u) kk[u] = umn(kk[u], p[7 - u]);
            CE(0,4) CE(1,5) CE(2,6) CE(3,7)
            CE(0,2) CE(1,3) CE(4,6) CE(5,7)
            CE(0,1) CE(2,3) CE(4,5) CE(6,7)
            // level d=8 (DPP row_ror:8), min only -- bitonic result holds
            // the exact top-8 multiset; merge_topk is order-independent.
            #pragma unroll
            for (int u = 0; u < 8; ++u) p[u] = dpp_xor8(kk[u]);
            #pragma unroll
            for (int u = 0; u < 8; ++u) kk[u] = umn(kk[u], p[7 - u]);

            if (m == 0) {
                uint4* dst = (uint4*)&blkTop[((size_t)grow * 64 + cblk) * 8];
                uint4 lo4 = { kk[0], kk[1], kk[2], kk[3] };
                uint4 hi4 = { kk[4], kk[5], kk[6], kk[7] };
                dst[0] = lo4;
                dst[1] = hi4;
            }
        }
    }
#undef CE
}

// Phase 1b: merge 64 blocks x 8 keys per row -> top-16 candidates.
// (Input chunk order is irrelevant: per-lane insertion sort + extract-min.)
// R16: min-reduction levels d=1,2,4,8 via DPP (VALU); only d=16,32 remain
// DS (cross-row-16 has no CDNA DPP encoding). 6 -> 2 DS ops per round;
// the 16 serial extract-min rounds' dependent chain shrinks accordingly.
__global__ void merge_topk_kernel(const unsigned* __restrict__ blkTop,
                                  int* __restrict__ cand) {
    const int wv   = threadIdx.x >> 6;
    const int lane = threadIdx.x & 63;
    const int row  = blockIdx.x * 4 + wv;
    const uint4* base = (const uint4*)(blkTop + (size_t)row * 512);

    uint4 a = base[lane * 2];
    uint4 b = base[lane * 2 + 1];
    unsigned in[8] = { a.x, a.y, a.z, a.w, b.x, b.y, b.z, b.w };
    unsigned kk[8];
    #pragma unroll
    for (int j = 0; j < 8; ++j) {
        kk[j] = in[j];
        #pragma unroll
        for (int s = 7; s > 0; --s) {
            if (s <= j) {
                unsigned lo = umn(kk[s - 1], kk[s]);
                unsigned hi = kk[s - 1] < kk[s] ? kk[s] : kk[s - 1];
                kk[s - 1] = lo; kk[s] = hi;
            }
        }
    }

    unsigned sval = 0;
    #pragma unroll
    for (int s = 0; s < NCAND; ++s) {
        unsigned g = kk[0];
        g = umn(g, (unsigned)__shfl_xor((int)g, 32, 64));
        g = umn(g, (unsigned)__shfl_xor((int)g, 16, 64));
        g = umn(g, dpp_xor8(g));
        g = umn(g, dpp_xor4(g));
        g = umn(g, dpp_xor2(g));
        g = umn(g, dpp_xor1(g));
        bool pop = (kk[0] == g);
        #pragma unroll
        for (int u = 0; u < 7; ++u) kk[u] = pop ? kk[u + 1] : kk[u];
        kk[7] = pop ? 0xFFFFFFFFu : kk[7];
        sval = (lane == s) ? g : sval;
    }
    if (lane < NCAND)
        cand[(size_t)row * NCAND + lane] = (int)(sval & 0xFFFFu);
}

// Phase 2: exact numpy-fp32 replica rescore (selection logic unchanged since
// R4) + FULL k_hot row write (zeros + the 4 ones in one pass; replaces the
// 512 MB memset). Untouched since R12 (proven-exact FMA codegen).
__global__ void rescore_kernel(const float* __restrict__ ze,
                               const float* __restrict__ cb,
                               const int* __restrict__ cand,
                               float* __restrict__ out_zq,
                               float* __restrict__ out_khot,
                               double* __restrict__ lossAcc) {
    __shared__ float zsh[4][DIM];
    const int wv = threadIdx.x >> 6;
    const int lane = threadIdx.x & 63;
    const int row = blockIdx.x * 4 + wv;

    {
        const float* zp = ze + (size_t)row * DIM + lane * 8;
        float4 v0 = *(const float4*)zp;
        float4 v1 = *(const float4*)(zp + 4);
        *(float4*)&zsh[wv][lane * 8]     = v0;
        *(float4*)&zsh[wv][lane * 8 + 4] = v1;
    }
    __syncthreads();

    // znorm, numpy-pairwise
    float racc = 0.0f;
    {
        const int b = (lane >> 3) & 3;
        const int j = lane & 7;
        const float* zr = &zsh[wv][128 * b + j];
        #pragma unroll
        for (int i = 0; i < 16; ++i) {
            float zk = zr[8 * i];
            float sq = zk * zk;
            asm volatile("" : "+v"(sq));   // block FMA contraction into the add
            racc = racc + sq;
        }
    }
    float t1 = racc + __shfl_xor(racc, 1, 64);
    float t2 = t1 + __shfl_xor(t1, 2, 64);
    float t3 = t2 + __shfl_xor(t2, 4, 64);
    float zn = (__shfl(t3, 0, 64) + __shfl(t3, 8, 64))
             + (__shfl(t3, 16, 64) + __shfl(t3, 24, 64));

    // candidate chains: KC=384 split, sequential FMA, single accumulator each
    float qv = 3.0e38f;
    int   idxv = 0x7fffffff;
    if (lane < NCAND) {
        idxv = cand[(size_t)row * NCAND + lane];
        const float* wp = cb + (size_t)idxv * DIM;
        const float* zz = zsh[wv];
        float acc1 = 0.0f;
        for (int k = 0; k < 384; k += 8) {
            float4 wa = *(const float4*)(wp + k);
            float4 wb = *(const float4*)(wp + k + 4);
            acc1 = __builtin_fmaf(zz[k + 0], wa.x, acc1);
            acc1 = __builtin_fmaf(zz[k + 1], wa.y, acc1);
            acc1 = __builtin_fmaf(zz[k + 2], wa.z, acc1);
            acc1 = __builtin_fmaf(zz[k + 3], wa.w, acc1);
            acc1 = __builtin_fmaf(zz[k + 4], wb.x, acc1);
            acc1 = __builtin_fmaf(zz[k + 5], wb.y, acc1);
            acc1 = __builtin_fmaf(zz[k + 6], wb.z, acc1);
            acc1 = __builtin_fmaf(zz[k + 7], wb.w, acc1);
        }
        float acc2 = 0.0f;
        for (int k = 384; k < 512; k += 8) {
            float4 wa = *(const float4*)(wp + k);
            float4 wb = *(const float4*)(wp + k + 4);
            acc2 = __builtin_fmaf(zz[k + 0], wa.x, acc2);
            acc2 = __builtin_fmaf(zz[k + 1], wa.y, acc2);
            acc2 = __builtin_fmaf(zz[k + 2], wa.z, acc2);
            acc2 = __builtin_fmaf(zz[k + 3], wa.w, acc2);
            acc2 = __builtin_fmaf(zz[k + 4], wb.x, acc2);
            acc2 = __builtin_fmaf(zz[k + 5], wb.y, acc2);
            acc2 = __builtin_fmaf(zz[k + 6], wb.z, acc2);
            acc2 = __builtin_fmaf(zz[k + 7], wb.w, acc2);
        }
        float Cv = acc1 + acc2;
        qv = zn - 2.0f * Cv;
    }

    float q[NCAND]; int id[NCAND];
    #pragma unroll
    for (int c = 0; c < NCAND; ++c) {
        q[c]  = __shfl(qv, c, 64);
        id[c] = __shfl(idxv, c, 64);
    }
    int selIdx[4];
    bool used[NCAND];
    #pragma unroll
    for (int c = 0; c < NCAND; ++c) used[c] = false;
    #pragma unroll
    for (int s = 0; s < 4; ++s) {
        float bq = 3.0e38f; int bi = 0x7fffffff; int bc = -1;
        #pragma unroll
        for (int c = 0; c < NCAND; ++c) {
            bool better = !used[c] && (q[c] < bq || (q[c] == bq && id[c] < bi));
            if (better) { bq = q[c]; bi = id[c]; bc = c; }
        }
        selIdx[s] = bi;
        #pragma unroll
        for (int c = 0; c < NCAND; ++c) used[c] = used[c] || (c == bc);
    }

    float zq[8] = { 0, 0, 0, 0, 0, 0, 0, 0 };
    #pragma unroll
    for (int s = 0; s < 4; ++s) {
        const float* wp = cb + (size_t)selIdx[s] * DIM + lane * 8;
        float4 w0 = *(const float4*)wp;
        float4 w1 = *(const float4*)(wp + 4);
        zq[0] += w0.x; zq[1] += w0.y; zq[2] += w0.z; zq[3] += w0.w;
        zq[4] += w1.x; zq[5] += w1.y; zq[6] += w1.z; zq[7] += w1.w;
    }

    float zf[8];
    {
        const float* zz = &zsh[wv][lane * 8];
        #pragma unroll
        for (int i = 0; i < 8; ++i) zf[i] = zz[i];
    }
    float o[8];
    double l = 0.0;
    #pragma unroll
    for (int i = 0; i < 8; ++i) {
        float zqf  = zq[i] * 0.25f;
        float diff = zqf - zf[i];
        o[i] = zf[i] + diff;
        double ld = (double)diff;
        l += ld * ld;
    }
    {
        float* op = out_zq + (size_t)row * DIM + lane * 8;
        float4 v0 = { o[0], o[1], o[2], o[3] };
        float4 v1 = { o[4], o[5], o[6], o[7] };
        *(float4*)op = v0;
        *(float4*)(op + 4) = v1;
    }
    #pragma unroll
    for (int mm = 32; mm; mm >>= 1) l += __shfl_xor(l, mm, 64);
    if (lane == 0) atomicAdd(lossAcc, l);

    // full k_hot row write: lane owns cols {j*256 + lane*4 + e}.
    // hot mask: col -> j = col>>8, e = col&3, owner lane = (col>>2)&63.
    unsigned hotm[4] = { 0u, 0u, 0u, 0u };
    #pragma unroll
    for (int s = 0; s < 4; ++s) {
        int si = selIdx[s];
        bool own = ((si >> 2) & 63) == lane;
        int jj = si >> 8;
        unsigned bit = 1u << (((jj & 7) << 2) | (si & 3));
        int word = jj >> 3;
        #pragma unroll
        for (int wd = 0; wd < 4; ++wd)
            hotm[wd] |= (own && word == wd) ? bit : 0u;
    }
    float* kp = out_khot + (size_t)row * N_EMB;
    #pragma unroll
    for (int j = 0; j < 32; ++j) {
        unsigned bits = (hotm[j >> 3] >> ((j & 7) * 4)) & 0xFu;
        float4 v;
        v.x = (bits & 1u) ? 1.0f : 0.0f;
        v.y = (bits & 2u) ? 1.0f : 0.0f;
        v.z = (bits & 4u) ? 1.0f : 0.0f;
        v.w = (bits & 8u) ? 1.0f : 0.0f;
        *(float4*)(kp + j * 256 + lane * 4) = v;
    }
}

__global__ void finalize_kernel(const double* __restrict__ lossAcc,
                                float* __restrict__ out_loss) {
    if (threadIdx.x == 0 && blockIdx.x == 0)
        out_loss[0] = (float)(lossAcc[0] * (1.25 / ((double)N_ROWS * (double)DIM)));
}

extern "C" void kernel_launch(void* const* d_in, const int* in_sizes, int n_in,
                              void* d_out, int out_size, void* d_ws, size_t ws_size,
                              hipStream_t stream) {
    (void)in_sizes; (void)n_in; (void)out_size; (void)ws_size;
    const float* ze = (const float*)d_in[0];
    const float* cb = (const float*)d_in[1];

    float* out      = (float*)d_out;
    float* out_zq   = out;                                   // [16384, 512]
    float* out_loss = out + (size_t)N_ROWS * DIM;            // [1]
    float* out_khot = out_loss + 1;                          // [16384, 8192]

    double* lossAcc = (double*)d_ws;
    int*    cand    = (int*)((char*)d_ws + 16);

    // scratch inside k_hot region, 16B-aligned, consumed before rescore
    char* base = (char*)d_out;
    unsigned*       blkTop = (unsigned*)(base + 33554448);                  // khot + 12 B
    unsigned short* ze16   = (unsigned short*)(base + 33554448 + 33554432); // + 32 MB
    unsigned short* cb16   = ze16 + (size_t)N_ROWS * DIM;

    hipMemsetAsync(lossAcc, 0, 16, stream);

    convert_bf16_kernel<<<6144, 256, 0, stream>>>(ze, cb, ze16, cb16);
    score_gemm_topk_kernel<<<8192, 256, 0, stream>>>(ze16, cb16, blkTop);
    merge_topk_kernel<<<N_ROWS / 4, 256, 0, stream>>>(blkTop, cand);
    rescore_kernel<<<N_ROWS / 4, 256, 0, stream>>>(ze, cb, cand, out_zq, out_khot, lossAcc);
    finalize_kernel<<<1, 64, 0, stream>>>(lossAcc, out_loss);
}